// Round 1
// baseline (173.878 us; speedup 1.0000x reference)
//
#include <hip/hip_runtime.h>
#include <math.h>

#define NQ   512
#define NKV  1280
#define CDIM 128
#define L2E  1.4426950408889634f

// workspace layout (float offsets)
#define OFF_WDSUM 0        // 3
#define OFF_SUMS  16       // 1024: [br][512] row sums (zeroed by prep)
#define OFF_QSA   1056     // 65536 [n=512][c=128]
#define OFF_QDA   66592    // 65536 (scaled by log2e)
#define OFF_KSAT  132128   // 163840 [c=128][k=1280]
#define OFF_VSA   295968   // 163840 [k=1280][c=128]
#define OFF_KDAT  459808   // 163840 (scaled by log2e)
#define OFF_VDA   623648   // 163840
#define OFF_OUT   787488   // 131072: [br][512][128] unnormalized AV (zeroed)
// total 918560 floats = 3.67 MB

// ---------------------------------------------------------------- prep
// bx<320: kv proj (4 keys); bx in [320,448): q proj (4 rows);
// bx==448: wdsum + zero sums; bx in [449,577): zero OUT.
__global__ __launch_bounds__(256) void prep_kernel(
    const float* __restrict__ erp, const float* __restrict__ ico,
    const float* __restrict__ wq_sa, const float* __restrict__ wq_da,
    const float* __restrict__ wkv_sa, const float* __restrict__ wkv_da,
    const float* __restrict__ wdelta, float* __restrict__ ws)
{
  int bx = blockIdx.x, t = threadIdx.x;
  if (bx < 320) {
    __shared__ float x4[4 * CDIM];          // [j*4 + ky]
    int k0 = bx * 4;
    for (int i = t; i < 512; i += 256) {
      int ky = i >> 7, j = i & 127;
      x4[j * 4 + ky] = ico[(k0 + ky) * CDIM + j];
    }
    __syncthreads();
    const float4* wsa4 = (const float4*)(wkv_sa + t * CDIM);
    const float4* wda4 = (const float4*)(wkv_da + t * CDIM);
    float as0=0,as1=0,as2=0,as3=0, ad0=0,ad1=0,ad2=0,ad3=0;
    #pragma unroll 4
    for (int j4 = 0; j4 < 32; ++j4) {
      float4 wsv = wsa4[j4];
      float4 wdv = wda4[j4];
      float4 x0 = *(const float4*)&x4[(j4 * 4 + 0) * 4];
      float4 x1 = *(const float4*)&x4[(j4 * 4 + 1) * 4];
      float4 x2 = *(const float4*)&x4[(j4 * 4 + 2) * 4];
      float4 x3 = *(const float4*)&x4[(j4 * 4 + 3) * 4];
      as0 = fmaf(wsv.x, x0.x, as0); as1 = fmaf(wsv.x, x0.y, as1);
      as2 = fmaf(wsv.x, x0.z, as2); as3 = fmaf(wsv.x, x0.w, as3);
      ad0 = fmaf(wdv.x, x0.x, ad0); ad1 = fmaf(wdv.x, x0.y, ad1);
      ad2 = fmaf(wdv.x, x0.z, ad2); ad3 = fmaf(wdv.x, x0.w, ad3);
      as0 = fmaf(wsv.y, x1.x, as0); as1 = fmaf(wsv.y, x1.y, as1);
      as2 = fmaf(wsv.y, x1.z, as2); as3 = fmaf(wsv.y, x1.w, as3);
      ad0 = fmaf(wdv.y, x1.x, ad0); ad1 = fmaf(wdv.y, x1.y, ad1);
      ad2 = fmaf(wdv.y, x1.z, ad2); ad3 = fmaf(wdv.y, x1.w, ad3);
      as0 = fmaf(wsv.z, x2.x, as0); as1 = fmaf(wsv.z, x2.y, as1);
      as2 = fmaf(wsv.z, x2.z, as2); as3 = fmaf(wsv.z, x2.w, as3);
      ad0 = fmaf(wdv.z, x2.x, ad0); ad1 = fmaf(wdv.z, x2.y, ad1);
      ad2 = fmaf(wdv.z, x2.z, ad2); ad3 = fmaf(wdv.z, x2.w, ad3);
      as0 = fmaf(wsv.w, x3.x, as0); as1 = fmaf(wsv.w, x3.y, as1);
      as2 = fmaf(wsv.w, x3.z, as2); as3 = fmaf(wsv.w, x3.w, as3);
      ad0 = fmaf(wdv.w, x3.x, ad0); ad1 = fmaf(wdv.w, x3.y, ad1);
      ad2 = fmaf(wdv.w, x3.z, ad2); ad3 = fmaf(wdv.w, x3.w, ad3);
    }
    if (t < 128) {   // k features -> transposed [c][k]; da scaled by log2e
      *(float4*)(ws + OFF_KSAT + t * NKV + k0) = make_float4(as0, as1, as2, as3);
      *(float4*)(ws + OFF_KDAT + t * NKV + k0) =
          make_float4(ad0 * L2E, ad1 * L2E, ad2 * L2E, ad3 * L2E);
    } else {         // v features -> [k][c] (unscaled)
      int c = t - 128;
      ws[OFF_VSA + (k0 + 0) * CDIM + c] = as0;
      ws[OFF_VSA + (k0 + 1) * CDIM + c] = as1;
      ws[OFF_VSA + (k0 + 2) * CDIM + c] = as2;
      ws[OFF_VSA + (k0 + 3) * CDIM + c] = as3;
      ws[OFF_VDA + (k0 + 0) * CDIM + c] = ad0;
      ws[OFF_VDA + (k0 + 1) * CDIM + c] = ad1;
      ws[OFF_VDA + (k0 + 2) * CDIM + c] = ad2;
      ws[OFF_VDA + (k0 + 3) * CDIM + c] = ad3;
    }
  } else if (bx < 448) {
    // q projection, 4 rows; t<128 -> q_sa out c=t, t>=128 -> q_da (log2e-scaled)
    __shared__ float q4[4 * CDIM];          // [j*4 + r]
    int n0 = (bx - 320) * 4;
    for (int i = t; i < 512; i += 256)
      q4[i] = erp[(i >> 2) * NQ + n0 + (i & 3)];
    __syncthreads();
    const float* w = (t < 128) ? wq_sa : wq_da;
    int c = t & 127;
    const float4* w4 = (const float4*)(w + c * CDIM);
    float a0 = 0.f, a1 = 0.f, a2 = 0.f, a3 = 0.f;
    #pragma unroll 8
    for (int j4 = 0; j4 < 32; ++j4) {
      float4 wv = w4[j4];
      float4 q0 = *(const float4*)&q4[(j4 * 4 + 0) * 4];
      float4 q1 = *(const float4*)&q4[(j4 * 4 + 1) * 4];
      float4 q2 = *(const float4*)&q4[(j4 * 4 + 2) * 4];
      float4 q3 = *(const float4*)&q4[(j4 * 4 + 3) * 4];
      a0 = fmaf(wv.x, q0.x, a0); a1 = fmaf(wv.x, q0.y, a1);
      a2 = fmaf(wv.x, q0.z, a2); a3 = fmaf(wv.x, q0.w, a3);
      a0 = fmaf(wv.y, q1.x, a0); a1 = fmaf(wv.y, q1.y, a1);
      a2 = fmaf(wv.y, q1.z, a2); a3 = fmaf(wv.y, q1.w, a3);
      a0 = fmaf(wv.z, q2.x, a0); a1 = fmaf(wv.z, q2.y, a1);
      a2 = fmaf(wv.z, q2.z, a2); a3 = fmaf(wv.z, q2.w, a3);
      a0 = fmaf(wv.w, q3.x, a0); a1 = fmaf(wv.w, q3.y, a1);
      a2 = fmaf(wv.w, q3.z, a2); a3 = fmaf(wv.w, q3.w, a3);
    }
    float sc = (t < 128) ? 1.0f : L2E;
    float* o = ws + ((t < 128) ? OFF_QSA : OFF_QDA);
    o[(n0 + 0) * CDIM + c] = a0 * sc;
    o[(n0 + 1) * CDIM + c] = a1 * sc;
    o[(n0 + 2) * CDIM + c] = a2 * sc;
    o[(n0 + 3) * CDIM + c] = a3 * sc;
  } else if (bx == 448) {
    *(float4*)(ws + OFF_SUMS + t * 4) = make_float4(0.f, 0.f, 0.f, 0.f);
    if (t < 3) {   // Wdelta.sum(0)
      float s = 0.f;
      for (int i = 0; i < 128; ++i) s += wdelta[i * 3 + t];
      ws[OFF_WDSUM + t] = s;
    }
  } else {
    int base = OFF_OUT + (bx - 449) * 1024 + t * 4;
    *(float4*)(ws + base) = make_float4(0.f, 0.f, 0.f, 0.f);
  }
}

// ---------------------------------------------------------------- attn
// 640 blocks, br = b&1 (da odd, sa even, interleaved for CU mix).
// Each block: 8 q-rows (g = bb/5), 256-k slice (z = bb%5).
// Thread t owns key k = k0+t: full 128-j logit (no partial merge), exp (via
// exp2 on pre-scaled data), se store, shuffle row-sums; AV splits k-range
// across the two thread-halves (V read exactly once), 8-row accumulators.
__global__ __launch_bounds__(256) void attn_kernel(
    const float* __restrict__ coord, float* __restrict__ ws)
{
  __shared__ __align__(16) float qjf[128][8];  // [j][r] 4KB
  __shared__ __align__(16) float se[8][256];   // exp(logit) 8KB
  __shared__ float red[4][8];
  __shared__ float qcr[8][3];                  // log2e-scaled (da)
  __shared__ float wdl[3];
  int b = blockIdx.x, t = threadIdx.x;
  int br = b & 1;
  int bb = b >> 1;
  int g = bb / 5, z = bb - g * 5;
  int n0 = g * 8, k0 = z * 256;

  const float* qsrc = ws + (br ? OFF_QDA : OFF_QSA);
  {
    int j = t & 127, r0 = t >> 7;   // r0 in {0,1}; rows r0, r0+2, r0+4, r0+6
    qjf[j][r0]     = qsrc[(n0 + r0)     * CDIM + j];
    qjf[j][r0 + 2] = qsrc[(n0 + r0 + 2) * CDIM + j];
    qjf[j][r0 + 4] = qsrc[(n0 + r0 + 4) * CDIM + j];
    qjf[j][r0 + 6] = qsrc[(n0 + r0 + 6) * CDIM + j];
  }
  if (br) {
    if (t < 8) {
      int n = n0 + t;
      float x = (float)(n & 31), y = (float)(n >> 5);
      float u  = (x - 16.5f) * 0.19634954084936207f;  // pi/16
      float vv = (y -  8.5f) * 0.19634954084936207f;
      float cv = cosf(vv);
      qcr[t][0] = cv * sinf(u) * L2E;
      qcr[t][1] = sinf(vv) * L2E;
      qcr[t][2] = cv * cosf(u) * L2E;
    }
    if (t >= 64 && t < 67) wdl[t - 64] = ws[OFF_WDSUM + (t - 64)];
  }
  __syncthreads();

  int kl = t, k = k0 + kl;
  float acc[8];
  #pragma unroll
  for (int r = 0; r < 8; ++r) acc[r] = 0.f;

  if (br) {
    const float* kp = ws + OFF_KDAT + k;   // pre-scaled by log2e
    #pragma unroll 2
    for (int j = 0; j < 128; ++j) {
      float kv = kp[j * NKV];
      float4 qa = *(const float4*)&qjf[j][0];
      float4 qb = *(const float4*)&qjf[j][4];
      acc[0] += exp2f(-fabsf(qa.x - kv));
      acc[1] += exp2f(-fabsf(qa.y - kv));
      acc[2] += exp2f(-fabsf(qa.z - kv));
      acc[3] += exp2f(-fabsf(qa.w - kv));
      acc[4] += exp2f(-fabsf(qb.x - kv));
      acc[5] += exp2f(-fabsf(qb.y - kv));
      acc[6] += exp2f(-fabsf(qb.z - kv));
      acc[7] += exp2f(-fabsf(qb.w - kv));
    }
  } else {
    const float* kp = ws + OFF_KSAT + k;
    #pragma unroll 4
    for (int j = 0; j < 128; ++j) {
      float kv = kp[j * NKV];
      float4 qa = *(const float4*)&qjf[j][0];
      float4 qb = *(const float4*)&qjf[j][4];
      acc[0] = fmaf(qa.x, kv, acc[0]);
      acc[1] = fmaf(qa.y, kv, acc[1]);
      acc[2] = fmaf(qa.z, kv, acc[2]);
      acc[3] = fmaf(qa.w, kv, acc[3]);
      acc[4] = fmaf(qb.x, kv, acc[4]);
      acc[5] = fmaf(qb.y, kv, acc[5]);
      acc[6] = fmaf(qb.z, kv, acc[6]);
      acc[7] = fmaf(qb.w, kv, acc[7]);
    }
  }

  float e[8];
  if (br) {
    float c0 = coord[3 * k]     * L2E;
    float c1 = coord[3 * k + 1] * L2E;
    float c2 = coord[3 * k + 2] * L2E;
    float w0 = wdl[0], w1 = wdl[1], w2 = wdl[2];
    #pragma unroll
    for (int r = 0; r < 8; ++r) {
      float pos = w0 * exp2f(-fabsf(qcr[r][0] - c0))
                + w1 * exp2f(-fabsf(qcr[r][1] - c1))
                + w2 * exp2f(-fabsf(qcr[r][2] - c2));
      e[r] = exp2f((acc[r] + pos) * (L2E / 128.0f));   // exp((feat+pos)/C)
    }
  } else {
    const float scl = 0.088388347648318447f * L2E;     // C^-0.5 * log2e
    #pragma unroll
    for (int r = 0; r < 8; ++r) e[r] = exp2f(acc[r] * scl);
  }
  #pragma unroll
  for (int r = 0; r < 8; ++r) se[r][kl] = e[r];

  // wave row-sums -> per-wave partials -> atomicAdd
  float s[8];
  #pragma unroll
  for (int r = 0; r < 8; ++r) s[r] = e[r];
  #pragma unroll
  for (int o = 32; o > 0; o >>= 1) {
    #pragma unroll
    for (int r = 0; r < 8; ++r) s[r] += __shfl_down(s[r], o, 64);
  }
  if ((t & 63) == 0) {
    int w = t >> 6;
    #pragma unroll
    for (int r = 0; r < 8; ++r) red[w][r] = s[r];
  }
  __syncthreads();   // covers se[] and red[]
  if (t < 8)
    atomicAdd(ws + OFF_SUMS + br * 512 + n0 + t,
              red[0][t] + red[1][t] + red[2][t] + red[3][t]);

  // AV: thread (c=t&127, h=t>>7) handles k-half [h*128, h*128+128), all 8 rows
  int c = t & 127, h = t >> 7;
  int kb = h * 128;
  const float* vp = ws + (br ? OFF_VDA : OFF_VSA) + (k0 + kb) * CDIM + c;
  float a[8];
  #pragma unroll
  for (int r = 0; r < 8; ++r) a[r] = 0.f;
  #pragma unroll 2
  for (int ko = 0; ko < 128; ko += 4) {
    float4 p0 = *(const float4*)&se[0][kb + ko];
    float4 p1 = *(const float4*)&se[1][kb + ko];
    float4 p2 = *(const float4*)&se[2][kb + ko];
    float4 p3 = *(const float4*)&se[3][kb + ko];
    float4 p4 = *(const float4*)&se[4][kb + ko];
    float4 p5 = *(const float4*)&se[5][kb + ko];
    float4 p6 = *(const float4*)&se[6][kb + ko];
    float4 p7 = *(const float4*)&se[7][kb + ko];
    float v0 = vp[(ko + 0) * CDIM];
    float v1 = vp[(ko + 1) * CDIM];
    float v2 = vp[(ko + 2) * CDIM];
    float v3 = vp[(ko + 3) * CDIM];
    a[0] = fmaf(p0.x, v0, a[0]); a[0] = fmaf(p0.y, v1, a[0]);
    a[0] = fmaf(p0.z, v2, a[0]); a[0] = fmaf(p0.w, v3, a[0]);
    a[1] = fmaf(p1.x, v0, a[1]); a[1] = fmaf(p1.y, v1, a[1]);
    a[1] = fmaf(p1.z, v2, a[1]); a[1] = fmaf(p1.w, v3, a[1]);
    a[2] = fmaf(p2.x, v0, a[2]); a[2] = fmaf(p2.y, v1, a[2]);
    a[2] = fmaf(p2.z, v2, a[2]); a[2] = fmaf(p2.w, v3, a[2]);
    a[3] = fmaf(p3.x, v0, a[3]); a[3] = fmaf(p3.y, v1, a[3]);
    a[3] = fmaf(p3.z, v2, a[3]); a[3] = fmaf(p3.w, v3, a[3]);
    a[4] = fmaf(p4.x, v0, a[4]); a[4] = fmaf(p4.y, v1, a[4]);
    a[4] = fmaf(p4.z, v2, a[4]); a[4] = fmaf(p4.w, v3, a[4]);
    a[5] = fmaf(p5.x, v0, a[5]); a[5] = fmaf(p5.y, v1, a[5]);
    a[5] = fmaf(p5.z, v2, a[5]); a[5] = fmaf(p5.w, v3, a[5]);
    a[6] = fmaf(p6.x, v0, a[6]); a[6] = fmaf(p6.y, v1, a[6]);
    a[6] = fmaf(p6.z, v2, a[6]); a[6] = fmaf(p6.w, v3, a[6]);
    a[7] = fmaf(p7.x, v0, a[7]); a[7] = fmaf(p7.y, v1, a[7]);
    a[7] = fmaf(p7.z, v2, a[7]); a[7] = fmaf(p7.w, v3, a[7]);
  }
  float* op = ws + OFF_OUT + br * (NQ * CDIM) + c;
  #pragma unroll
  for (int r = 0; r < 8; ++r)
    atomicAdd(op + (n0 + r) * CDIM, a[r]);
}

// ---------------------------------------------------------------- finalize
// one block (256 thr) per 2 query rows: normalize (divide by sums) with the
// reference's transpose-reshape on sa, project both, gate, fuse, NCHW store.
__global__ __launch_bounds__(256) void finalize_kernel(
    const float* __restrict__ psa, const float* __restrict__ bsa,
    const float* __restrict__ pda, const float* __restrict__ bda,
    const float* __restrict__ gsa, const float* __restrict__ gda,
    float* __restrict__ out, float* __restrict__ ws)
{
  __shared__ float sain[2][CDIM];
  __shared__ float dain[2][CDIM];
  __shared__ float cat[2][2 * CDIM];
  __shared__ float gl[2][2][CDIM];
  int i0 = blockIdx.x * 2, t = threadIdx.x;
  int h = t >> 7, c = t & 127;
  #pragma unroll
  for (int rr = 0; rr < 2; ++rr) {
    int i = i0 + rr;
    if (h == 0) {
      int row = (i & 3) * 128 + c;
      float s = ws[OFF_SUMS + row];
      sain[rr][c] = ws[OFF_OUT + row * CDIM + (i >> 2)] / s;
    } else {
      float s = ws[OFF_SUMS + 512 + i];
      dain[rr][c] = ws[OFF_OUT + NQ * CDIM + i * CDIM + c] / s;
    }
  }
  __syncthreads();
  {
    const float4* w4 = (const float4*)((h ? pda : psa) + c * CDIM);
    const float* in0 = h ? dain[0] : sain[0];
    const float* in1 = h ? dain[1] : sain[1];
    float a0 = 0, a1 = 0, b0 = 0, b1 = 0;
    #pragma unroll 8
    for (int j4 = 0; j4 < 32; ++j4) {
      float4 wv = w4[j4];
      float4 x0 = *(const float4*)&in0[j4 * 4];
      float4 x1 = *(const float4*)&in1[j4 * 4];
      a0 = fmaf(wv.x, x0.x, a0); a1 = fmaf(wv.y, x0.y, a1);
      a0 = fmaf(wv.z, x0.z, a0); a1 = fmaf(wv.w, x0.w, a1);
      b0 = fmaf(wv.x, x1.x, b0); b1 = fmaf(wv.y, x1.y, b1);
      b0 = fmaf(wv.z, x1.z, b0); b1 = fmaf(wv.w, x1.w, b1);
    }
    float bias = h ? bda[c] : bsa[c];
    cat[0][h * CDIM + c] = bias + a0 + a1;
    cat[1][h * CDIM + c] = bias + b0 + b1;
  }
  __syncthreads();
  {
    const float4* g4 = (const float4*)((h ? gda : gsa) + c * 2 * CDIM);
    float a0 = 0, a1 = 0, b0 = 0, b1 = 0;
    #pragma unroll 8
    for (int j4 = 0; j4 < 64; ++j4) {
      float4 gv = g4[j4];
      float4 c0 = *(const float4*)&cat[0][j4 * 4];
      float4 c1 = *(const float4*)&cat[1][j4 * 4];
      a0 = fmaf(gv.x, c0.x, a0); a1 = fmaf(gv.y, c0.y, a1);
      a0 = fmaf(gv.z, c0.z, a0); a1 = fmaf(gv.w, c0.w, a1);
      b0 = fmaf(gv.x, c1.x, b0); b1 = fmaf(gv.y, c1.y, b1);
      b0 = fmaf(gv.z, c1.z, b0); b1 = fmaf(gv.w, c1.w, b1);
    }
    gl[0][h][c] = 1.0f / (1.0f + __expf(-(a0 + a1)));
    gl[1][h][c] = 1.0f / (1.0f + __expf(-(b0 + b1)));
  }
  __syncthreads();
  {
    int i = i0 + h;
    out[c * NQ + i] = gl[h][0][c] * cat[h][c] + gl[h][1][c] * cat[h][CDIM + c];
  }
}

// ---------------------------------------------------------------- launch
extern "C" void kernel_launch(void* const* d_in, const int* in_sizes, int n_in,
                              void* d_out, int out_size, void* d_ws, size_t ws_size,
                              hipStream_t stream)
{
  (void)in_sizes; (void)n_in; (void)out_size; (void)ws_size;
  const float* erp       = (const float*)d_in[0];
  const float* ico       = (const float*)d_in[1];
  const float* coord     = (const float*)d_in[2];
  const float* wq_sa     = (const float*)d_in[3];
  const float* wkv_sa    = (const float*)d_in[4];
  const float* proj_sa_w = (const float*)d_in[5];
  const float* proj_sa_b = (const float*)d_in[6];
  const float* wq_da     = (const float*)d_in[7];
  const float* wkv_da    = (const float*)d_in[8];
  const float* wdelta    = (const float*)d_in[9];
  const float* proj_da_w = (const float*)d_in[10];
  const float* proj_da_b = (const float*)d_in[11];
  const float* gate_sa   = (const float*)d_in[12];
  const float* gate_da   = (const float*)d_in[13];
  float* out = (float*)d_out;
  float* ws  = (float*)d_ws;

  hipLaunchKernelGGL(prep_kernel, dim3(577), dim3(256), 0, stream,
                     erp, ico, wq_sa, wq_da, wkv_sa, wkv_da, wdelta, ws);
  hipLaunchKernelGGL(attn_kernel, dim3(640), dim3(256), 0, stream,
                     coord, ws);
  hipLaunchKernelGGL(finalize_kernel, dim3(256), dim3(256), 0, stream,
                     proj_sa_w, proj_sa_b, proj_da_w, proj_da_b,
                     gate_sa, gate_da, out, ws);
}

// Round 2
// 171.411 us; speedup vs baseline: 1.0144x; 1.0144x over previous
//
#include <hip/hip_runtime.h>
#include <math.h>

#define NQ   512
#define NKV  1280
#define CDIM 128
#define L2E  1.4426950408889634f

// workspace layout (float offsets)
#define OFF_WDSUM 0        // 3
#define OFF_SUMS  16       // 1024: [br][512] row sums (zeroed by prep)
#define OFF_QSA   1056     // 65536 [n=512][c=128]
#define OFF_QDA   66592    // 65536 (scaled by log2e)
#define OFF_KSA   132128   // 163840 [k=1280][c=128] row-major
#define OFF_VSAT  295968   // 163840 [c=128][k=1280] transposed
#define OFF_KDA   459808   // 163840 [k][c] row-major (scaled by log2e)
#define OFF_VDAT  623648   // 163840 [c][k] transposed
#define OFF_OUT   787488   // 131072: [br][512][128] unnormalized AV (zeroed)
// total 918560 floats = 3.67 MB

// ---------------------------------------------------------------- prep
// bx<320: kv proj (4 keys); bx in [320,448): q proj (4 rows);
// bx==448: wdsum + zero sums; bx in [449,577): zero OUT.
__global__ __launch_bounds__(256) void prep_kernel(
    const float* __restrict__ erp, const float* __restrict__ ico,
    const float* __restrict__ wq_sa, const float* __restrict__ wq_da,
    const float* __restrict__ wkv_sa, const float* __restrict__ wkv_da,
    const float* __restrict__ wdelta, float* __restrict__ ws)
{
  int bx = blockIdx.x, t = threadIdx.x;
  if (bx < 320) {
    __shared__ float x4[4 * CDIM];          // [j*4 + ky]
    int k0 = bx * 4;
    for (int i = t; i < 512; i += 256) {
      int ky = i >> 7, j = i & 127;
      x4[j * 4 + ky] = ico[(k0 + ky) * CDIM + j];
    }
    __syncthreads();
    const float4* wsa4 = (const float4*)(wkv_sa + t * CDIM);
    const float4* wda4 = (const float4*)(wkv_da + t * CDIM);
    float as0=0,as1=0,as2=0,as3=0, ad0=0,ad1=0,ad2=0,ad3=0;
    #pragma unroll 4
    for (int j4 = 0; j4 < 32; ++j4) {
      float4 wsv = wsa4[j4];
      float4 wdv = wda4[j4];
      float4 x0 = *(const float4*)&x4[(j4 * 4 + 0) * 4];
      float4 x1 = *(const float4*)&x4[(j4 * 4 + 1) * 4];
      float4 x2 = *(const float4*)&x4[(j4 * 4 + 2) * 4];
      float4 x3 = *(const float4*)&x4[(j4 * 4 + 3) * 4];
      as0 = fmaf(wsv.x, x0.x, as0); as1 = fmaf(wsv.x, x0.y, as1);
      as2 = fmaf(wsv.x, x0.z, as2); as3 = fmaf(wsv.x, x0.w, as3);
      ad0 = fmaf(wdv.x, x0.x, ad0); ad1 = fmaf(wdv.x, x0.y, ad1);
      ad2 = fmaf(wdv.x, x0.z, ad2); ad3 = fmaf(wdv.x, x0.w, ad3);
      as0 = fmaf(wsv.y, x1.x, as0); as1 = fmaf(wsv.y, x1.y, as1);
      as2 = fmaf(wsv.y, x1.z, as2); as3 = fmaf(wsv.y, x1.w, as3);
      ad0 = fmaf(wdv.y, x1.x, ad0); ad1 = fmaf(wdv.y, x1.y, ad1);
      ad2 = fmaf(wdv.y, x1.z, ad2); ad3 = fmaf(wdv.y, x1.w, ad3);
      as0 = fmaf(wsv.z, x2.x, as0); as1 = fmaf(wsv.z, x2.y, as1);
      as2 = fmaf(wsv.z, x2.z, as2); as3 = fmaf(wsv.z, x2.w, as3);
      ad0 = fmaf(wdv.z, x2.x, ad0); ad1 = fmaf(wdv.z, x2.y, ad1);
      ad2 = fmaf(wdv.z, x2.z, ad2); ad3 = fmaf(wdv.z, x2.w, ad3);
      as0 = fmaf(wsv.w, x3.x, as0); as1 = fmaf(wsv.w, x3.y, as1);
      as2 = fmaf(wsv.w, x3.z, as2); as3 = fmaf(wsv.w, x3.w, as3);
      ad0 = fmaf(wdv.w, x3.x, ad0); ad1 = fmaf(wdv.w, x3.y, ad1);
      ad2 = fmaf(wdv.w, x3.z, ad2); ad3 = fmaf(wdv.w, x3.w, ad3);
    }
    if (t < 128) {   // k features -> row-major [k][c]; da scaled by log2e
      int c = t;
      ws[OFF_KSA + (k0 + 0) * CDIM + c] = as0;
      ws[OFF_KSA + (k0 + 1) * CDIM + c] = as1;
      ws[OFF_KSA + (k0 + 2) * CDIM + c] = as2;
      ws[OFF_KSA + (k0 + 3) * CDIM + c] = as3;
      ws[OFF_KDA + (k0 + 0) * CDIM + c] = ad0 * L2E;
      ws[OFF_KDA + (k0 + 1) * CDIM + c] = ad1 * L2E;
      ws[OFF_KDA + (k0 + 2) * CDIM + c] = ad2 * L2E;
      ws[OFF_KDA + (k0 + 3) * CDIM + c] = ad3 * L2E;
    } else {         // v features -> transposed [c][k], float4 along k
      int c = t - 128;
      *(float4*)(ws + OFF_VSAT + c * NKV + k0) = make_float4(as0, as1, as2, as3);
      *(float4*)(ws + OFF_VDAT + c * NKV + k0) = make_float4(ad0, ad1, ad2, ad3);
    }
  } else if (bx < 448) {
    // q projection, 4 rows; t<128 -> q_sa out c=t, t>=128 -> q_da (log2e-scaled)
    __shared__ float q4[4 * CDIM];          // [j*4 + r]
    int n0 = (bx - 320) * 4;
    for (int i = t; i < 512; i += 256)
      q4[i] = erp[(i >> 2) * NQ + n0 + (i & 3)];
    __syncthreads();
    const float* w = (t < 128) ? wq_sa : wq_da;
    int c = t & 127;
    const float4* w4 = (const float4*)(w + c * CDIM);
    float a0 = 0.f, a1 = 0.f, a2 = 0.f, a3 = 0.f;
    #pragma unroll 8
    for (int j4 = 0; j4 < 32; ++j4) {
      float4 wv = w4[j4];
      float4 q0 = *(const float4*)&q4[(j4 * 4 + 0) * 4];
      float4 q1 = *(const float4*)&q4[(j4 * 4 + 1) * 4];
      float4 q2 = *(const float4*)&q4[(j4 * 4 + 2) * 4];
      float4 q3 = *(const float4*)&q4[(j4 * 4 + 3) * 4];
      a0 = fmaf(wv.x, q0.x, a0); a1 = fmaf(wv.x, q0.y, a1);
      a2 = fmaf(wv.x, q0.z, a2); a3 = fmaf(wv.x, q0.w, a3);
      a0 = fmaf(wv.y, q1.x, a0); a1 = fmaf(wv.y, q1.y, a1);
      a2 = fmaf(wv.y, q1.z, a2); a3 = fmaf(wv.y, q1.w, a3);
      a0 = fmaf(wv.z, q2.x, a0); a1 = fmaf(wv.z, q2.y, a1);
      a2 = fmaf(wv.z, q2.z, a2); a3 = fmaf(wv.z, q2.w, a3);
      a0 = fmaf(wv.w, q3.x, a0); a1 = fmaf(wv.w, q3.y, a1);
      a2 = fmaf(wv.w, q3.z, a2); a3 = fmaf(wv.w, q3.w, a3);
    }
    float sc = (t < 128) ? 1.0f : L2E;
    float* o = ws + ((t < 128) ? OFF_QSA : OFF_QDA);
    o[(n0 + 0) * CDIM + c] = a0 * sc;
    o[(n0 + 1) * CDIM + c] = a1 * sc;
    o[(n0 + 2) * CDIM + c] = a2 * sc;
    o[(n0 + 3) * CDIM + c] = a3 * sc;
  } else if (bx == 448) {
    *(float4*)(ws + OFF_SUMS + t * 4) = make_float4(0.f, 0.f, 0.f, 0.f);
    if (t < 3) {   // Wdelta.sum(0)
      float s = 0.f;
      for (int i = 0; i < 128; ++i) s += wdelta[i * 3 + t];
      ws[OFF_WDSUM + t] = s;
    }
  } else {
    int base = OFF_OUT + (bx - 449) * 1024 + t * 4;
    *(float4*)(ws + base) = make_float4(0.f, 0.f, 0.f, 0.f);
  }
}

// ---------------------------------------------------------------- attn
// 1280 blocks, br = b&1 (da odd / sa even, interleaved for CU mix).
// Each block: 4 q-rows (g = (b>>1)/5), 256-k slice (z = (b>>1)%5).
// Thread t owns key k = k0+t: reads row k of K row-major as float4 (32 loads,
// 16 FMA/exp per load), computes all 4 row logits; exp2 on pre-scaled data;
// se -> LDS; shuffle row sums -> atomicAdd.  AV: thread (c,h) reads V^T[c]
// float4 over its 128-k half, se reads are wave-broadcast; 4-row atomicAdd.
__global__ __launch_bounds__(256) void attn_kernel(
    const float* __restrict__ coord, float* __restrict__ ws)
{
  __shared__ __align__(16) float qjf[128][4];  // [j][r] 2KB, float4 per j
  __shared__ __align__(16) float se[4][256];   // exp(logit) 4KB
  __shared__ float red[4][4];
  __shared__ float qcr[4][3];                  // log2e-scaled (da)
  __shared__ float wdl[3];
  int b = blockIdx.x, t = threadIdx.x;
  int br = b & 1;
  int bb = b >> 1;
  int g = bb / 5, z = bb - g * 5;
  int n0 = g * 4, k0 = z * 256;

  const float* qsrc = ws + (br ? OFF_QDA : OFF_QSA);
  {
    int j = t & 127, rh = t >> 7;   // rows rh, rh+2
    qjf[j][rh]     = qsrc[(n0 + rh)     * CDIM + j];
    qjf[j][rh + 2] = qsrc[(n0 + rh + 2) * CDIM + j];
  }
  if (br) {
    if (t < 4) {
      int n = n0 + t;
      float x = (float)(n & 31), y = (float)(n >> 5);
      float u  = (x - 16.5f) * 0.19634954084936207f;  // pi/16
      float vv = (y -  8.5f) * 0.19634954084936207f;
      float cv = cosf(vv);
      qcr[t][0] = cv * sinf(u) * L2E;
      qcr[t][1] = sinf(vv) * L2E;
      qcr[t][2] = cv * cosf(u) * L2E;
    }
    if (t >= 64 && t < 67) wdl[t - 64] = ws[OFF_WDSUM + (t - 64)];
  }
  __syncthreads();

  int k = k0 + t;
  float acc0 = 0.f, acc1 = 0.f, acc2 = 0.f, acc3 = 0.f;

  if (br) {
    const float4* kp = (const float4*)(ws + OFF_KDA + k * CDIM);
    #pragma unroll 4
    for (int j4 = 0; j4 < 32; ++j4) {
      float4 kv = kp[j4];
      float4 q0 = *(const float4*)qjf[j4 * 4 + 0];
      float4 q1 = *(const float4*)qjf[j4 * 4 + 1];
      float4 q2 = *(const float4*)qjf[j4 * 4 + 2];
      float4 q3 = *(const float4*)qjf[j4 * 4 + 3];
      acc0 += exp2f(-fabsf(q0.x - kv.x)); acc0 += exp2f(-fabsf(q1.x - kv.y));
      acc0 += exp2f(-fabsf(q2.x - kv.z)); acc0 += exp2f(-fabsf(q3.x - kv.w));
      acc1 += exp2f(-fabsf(q0.y - kv.x)); acc1 += exp2f(-fabsf(q1.y - kv.y));
      acc1 += exp2f(-fabsf(q2.y - kv.z)); acc1 += exp2f(-fabsf(q3.y - kv.w));
      acc2 += exp2f(-fabsf(q0.z - kv.x)); acc2 += exp2f(-fabsf(q1.z - kv.y));
      acc2 += exp2f(-fabsf(q2.z - kv.z)); acc2 += exp2f(-fabsf(q3.z - kv.w));
      acc3 += exp2f(-fabsf(q0.w - kv.x)); acc3 += exp2f(-fabsf(q1.w - kv.y));
      acc3 += exp2f(-fabsf(q2.w - kv.z)); acc3 += exp2f(-fabsf(q3.w - kv.w));
    }
  } else {
    const float4* kp = (const float4*)(ws + OFF_KSA + k * CDIM);
    #pragma unroll 4
    for (int j4 = 0; j4 < 32; ++j4) {
      float4 kv = kp[j4];
      float4 q0 = *(const float4*)qjf[j4 * 4 + 0];
      float4 q1 = *(const float4*)qjf[j4 * 4 + 1];
      float4 q2 = *(const float4*)qjf[j4 * 4 + 2];
      float4 q3 = *(const float4*)qjf[j4 * 4 + 3];
      acc0 = fmaf(q0.x, kv.x, acc0); acc0 = fmaf(q1.x, kv.y, acc0);
      acc0 = fmaf(q2.x, kv.z, acc0); acc0 = fmaf(q3.x, kv.w, acc0);
      acc1 = fmaf(q0.y, kv.x, acc1); acc1 = fmaf(q1.y, kv.y, acc1);
      acc1 = fmaf(q2.y, kv.z, acc1); acc1 = fmaf(q3.y, kv.w, acc1);
      acc2 = fmaf(q0.z, kv.x, acc2); acc2 = fmaf(q1.z, kv.y, acc2);
      acc2 = fmaf(q2.z, kv.z, acc2); acc2 = fmaf(q3.z, kv.w, acc2);
      acc3 = fmaf(q0.w, kv.x, acc3); acc3 = fmaf(q1.w, kv.y, acc3);
      acc3 = fmaf(q2.w, kv.z, acc3); acc3 = fmaf(q3.w, kv.w, acc3);
    }
  }

  float e0, e1, e2, e3;
  if (br) {
    float c0 = coord[3 * k]     * L2E;
    float c1 = coord[3 * k + 1] * L2E;
    float c2 = coord[3 * k + 2] * L2E;
    float w0 = wdl[0], w1 = wdl[1], w2 = wdl[2];
    float p0 = w0 * exp2f(-fabsf(qcr[0][0] - c0))
             + w1 * exp2f(-fabsf(qcr[0][1] - c1))
             + w2 * exp2f(-fabsf(qcr[0][2] - c2));
    float p1 = w0 * exp2f(-fabsf(qcr[1][0] - c0))
             + w1 * exp2f(-fabsf(qcr[1][1] - c1))
             + w2 * exp2f(-fabsf(qcr[1][2] - c2));
    float p2 = w0 * exp2f(-fabsf(qcr[2][0] - c0))
             + w1 * exp2f(-fabsf(qcr[2][1] - c1))
             + w2 * exp2f(-fabsf(qcr[2][2] - c2));
    float p3 = w0 * exp2f(-fabsf(qcr[3][0] - c0))
             + w1 * exp2f(-fabsf(qcr[3][1] - c1))
             + w2 * exp2f(-fabsf(qcr[3][2] - c2));
    const float lsc = L2E / 128.0f;
    e0 = exp2f((acc0 + p0) * lsc);
    e1 = exp2f((acc1 + p1) * lsc);
    e2 = exp2f((acc2 + p2) * lsc);
    e3 = exp2f((acc3 + p3) * lsc);
  } else {
    const float scl = 0.088388347648318447f * L2E;     // C^-0.5 * log2e
    e0 = exp2f(acc0 * scl);
    e1 = exp2f(acc1 * scl);
    e2 = exp2f(acc2 * scl);
    e3 = exp2f(acc3 * scl);
  }
  se[0][t] = e0; se[1][t] = e1; se[2][t] = e2; se[3][t] = e3;

  // wave row-sums -> per-wave partials -> atomicAdd
  float s0 = e0, s1 = e1, s2 = e2, s3 = e3;
  #pragma unroll
  for (int o = 32; o > 0; o >>= 1) {
    s0 += __shfl_down(s0, o, 64); s1 += __shfl_down(s1, o, 64);
    s2 += __shfl_down(s2, o, 64); s3 += __shfl_down(s3, o, 64);
  }
  if ((t & 63) == 0) {
    int w = t >> 6;
    red[w][0] = s0; red[w][1] = s1; red[w][2] = s2; red[w][3] = s3;
  }
  __syncthreads();   // covers se[] and red[]
  if (t < 4)
    atomicAdd(ws + OFF_SUMS + br * 512 + n0 + t,
              red[0][t] + red[1][t] + red[2][t] + red[3][t]);

  // AV: thread (c=t&127, h=t>>7) handles k-half [h*128, h*128+128), 4 rows.
  // V^T[c] read as float4 along k; se reads are wave-uniform (broadcast).
  int c = t & 127, h = t >> 7;
  int kb = h * 128;
  const float4* vp = (const float4*)(ws + (br ? OFF_VDAT : OFF_VSAT)
                                     + c * NKV + k0 + kb);
  float a0 = 0.f, a1 = 0.f, a2 = 0.f, a3 = 0.f;
  #pragma unroll 4
  for (int q4 = 0; q4 < 32; ++q4) {
    float4 vv = vp[q4];
    float4 p0 = *(const float4*)&se[0][kb + q4 * 4];
    float4 p1 = *(const float4*)&se[1][kb + q4 * 4];
    float4 p2 = *(const float4*)&se[2][kb + q4 * 4];
    float4 p3 = *(const float4*)&se[3][kb + q4 * 4];
    a0 = fmaf(p0.x, vv.x, a0); a0 = fmaf(p0.y, vv.y, a0);
    a0 = fmaf(p0.z, vv.z, a0); a0 = fmaf(p0.w, vv.w, a0);
    a1 = fmaf(p1.x, vv.x, a1); a1 = fmaf(p1.y, vv.y, a1);
    a1 = fmaf(p1.z, vv.z, a1); a1 = fmaf(p1.w, vv.w, a1);
    a2 = fmaf(p2.x, vv.x, a2); a2 = fmaf(p2.y, vv.y, a2);
    a2 = fmaf(p2.z, vv.z, a2); a2 = fmaf(p2.w, vv.w, a2);
    a3 = fmaf(p3.x, vv.x, a3); a3 = fmaf(p3.y, vv.y, a3);
    a3 = fmaf(p3.z, vv.z, a3); a3 = fmaf(p3.w, vv.w, a3);
  }
  float* op = ws + OFF_OUT + br * (NQ * CDIM) + c;
  atomicAdd(op + (n0 + 0) * CDIM, a0);
  atomicAdd(op + (n0 + 1) * CDIM, a1);
  atomicAdd(op + (n0 + 2) * CDIM, a2);
  atomicAdd(op + (n0 + 3) * CDIM, a3);
}

// ---------------------------------------------------------------- finalize
// one block (256 thr) per 2 query rows: normalize (divide by sums) with the
// reference's transpose-reshape on sa, project both, gate, fuse, NCHW store.
__global__ __launch_bounds__(256) void finalize_kernel(
    const float* __restrict__ psa, const float* __restrict__ bsa,
    const float* __restrict__ pda, const float* __restrict__ bda,
    const float* __restrict__ gsa, const float* __restrict__ gda,
    float* __restrict__ out, float* __restrict__ ws)
{
  __shared__ float sain[2][CDIM];
  __shared__ float dain[2][CDIM];
  __shared__ float cat[2][2 * CDIM];
  __shared__ float gl[2][2][CDIM];
  int i0 = blockIdx.x * 2, t = threadIdx.x;
  int h = t >> 7, c = t & 127;
  #pragma unroll
  for (int rr = 0; rr < 2; ++rr) {
    int i = i0 + rr;
    if (h == 0) {
      int row = (i & 3) * 128 + c;
      float s = ws[OFF_SUMS + row];
      sain[rr][c] = ws[OFF_OUT + row * CDIM + (i >> 2)] / s;
    } else {
      float s = ws[OFF_SUMS + 512 + i];
      dain[rr][c] = ws[OFF_OUT + NQ * CDIM + i * CDIM + c] / s;
    }
  }
  __syncthreads();
  {
    const float4* w4 = (const float4*)((h ? pda : psa) + c * CDIM);
    const float* in0 = h ? dain[0] : sain[0];
    const float* in1 = h ? dain[1] : sain[1];
    float a0 = 0, a1 = 0, b0 = 0, b1 = 0;
    #pragma unroll 8
    for (int j4 = 0; j4 < 32; ++j4) {
      float4 wv = w4[j4];
      float4 x0 = *(const float4*)&in0[j4 * 4];
      float4 x1 = *(const float4*)&in1[j4 * 4];
      a0 = fmaf(wv.x, x0.x, a0); a1 = fmaf(wv.y, x0.y, a1);
      a0 = fmaf(wv.z, x0.z, a0); a1 = fmaf(wv.w, x0.w, a1);
      b0 = fmaf(wv.x, x1.x, b0); b1 = fmaf(wv.y, x1.y, b1);
      b0 = fmaf(wv.z, x1.z, b0); b1 = fmaf(wv.w, x1.w, b1);
    }
    float bias = h ? bda[c] : bsa[c];
    cat[0][h * CDIM + c] = bias + a0 + a1;
    cat[1][h * CDIM + c] = bias + b0 + b1;
  }
  __syncthreads();
  {
    const float4* g4 = (const float4*)((h ? gda : gsa) + c * 2 * CDIM);
    float a0 = 0, a1 = 0, b0 = 0, b1 = 0;
    #pragma unroll 8
    for (int j4 = 0; j4 < 64; ++j4) {
      float4 gv = g4[j4];
      float4 c0 = *(const float4*)&cat[0][j4 * 4];
      float4 c1 = *(const float4*)&cat[1][j4 * 4];
      a0 = fmaf(gv.x, c0.x, a0); a1 = fmaf(gv.y, c0.y, a1);
      a0 = fmaf(gv.z, c0.z, a0); a1 = fmaf(gv.w, c0.w, a1);
      b0 = fmaf(gv.x, c1.x, b0); b1 = fmaf(gv.y, c1.y, b1);
      b0 = fmaf(gv.z, c1.z, b0); b1 = fmaf(gv.w, c1.w, b1);
    }
    gl[0][h][c] = 1.0f / (1.0f + __expf(-(a0 + a1)));
    gl[1][h][c] = 1.0f / (1.0f + __expf(-(b0 + b1)));
  }
  __syncthreads();
  {
    int i = i0 + h;
    out[c * NQ + i] = gl[h][0][c] * cat[h][c] + gl[h][1][c] * cat[h][CDIM + c];
  }
}

// ---------------------------------------------------------------- launch
extern "C" void kernel_launch(void* const* d_in, const int* in_sizes, int n_in,
                              void* d_out, int out_size, void* d_ws, size_t ws_size,
                              hipStream_t stream)
{
  (void)in_sizes; (void)n_in; (void)out_size; (void)ws_size;
  const float* erp       = (const float*)d_in[0];
  const float* ico       = (const float*)d_in[1];
  const float* coord     = (const float*)d_in[2];
  const float* wq_sa     = (const float*)d_in[3];
  const float* wkv_sa    = (const float*)d_in[4];
  const float* proj_sa_w = (const float*)d_in[5];
  const float* proj_sa_b = (const float*)d_in[6];
  const float* wq_da     = (const float*)d_in[7];
  const float* wkv_da    = (const float*)d_in[8];
  const float* wdelta    = (const float*)d_in[9];
  const float* proj_da_w = (const float*)d_in[10];
  const float* proj_da_b = (const float*)d_in[11];
  const float* gate_sa   = (const float*)d_in[12];
  const float* gate_da   = (const float*)d_in[13];
  float* out = (float*)d_out;
  float* ws  = (float*)d_ws;

  hipLaunchKernelGGL(prep_kernel, dim3(577), dim3(256), 0, stream,
                     erp, ico, wq_sa, wq_da, wkv_sa, wkv_da, wdelta, ws);
  hipLaunchKernelGGL(attn_kernel, dim3(1280), dim3(256), 0, stream,
                     coord, ws);
  hipLaunchKernelGGL(finalize_kernel, dim3(256), dim3(256), 0, stream,
                     proj_sa_w, proj_sa_b, proj_da_w, proj_da_b,
                     gate_sa, gate_da, out, ws);
}

// Round 3
// 146.962 us; speedup vs baseline: 1.1831x; 1.1664x over previous
//
#include <hip/hip_runtime.h>
#include <math.h>

#define NQ   512
#define NKV  1280
#define CDIM 128

// workspace layout (float offsets)
#define OFF_WDSUM 0        // 3
#define OFF_SUMS  16       // 1024: [br][512] row sums (zeroed by prep)
#define OFF_QSA   1056     // 65536 [n=512][c=128]
#define OFF_QDA   66592    // 65536
#define OFF_KSAT  132128   // 163840 [c=128][k=1280] transposed (coalesced score)
#define OFF_VSA   295968   // 163840 [k=1280][c=128] row-major (coalesced AV)
#define OFF_KDAT  459808   // 163840
#define OFF_VDA   623648   // 163840
#define OFF_OUT   787488   // 131072: [br][512][128] unnormalized AV (zeroed)
// total 918560 floats = 3.67 MB

// ---------------------------------------------------------------- prep
// bx<320: kv proj (4 keys); bx in [320,448): q proj (4 rows);
// bx==448: wdsum + zero sums; bx in [449,577): zero OUT.
__global__ __launch_bounds__(256) void prep_kernel(
    const float* __restrict__ erp, const float* __restrict__ ico,
    const float* __restrict__ wq_sa, const float* __restrict__ wq_da,
    const float* __restrict__ wkv_sa, const float* __restrict__ wkv_da,
    const float* __restrict__ wdelta, float* __restrict__ ws)
{
  int bx = blockIdx.x, t = threadIdx.x;
  if (bx < 320) {
    __shared__ float x4[4 * CDIM];          // [j*4 + ky]
    int k0 = bx * 4;
    for (int i = t; i < 512; i += 256) {
      int ky = i >> 7, j = i & 127;
      x4[j * 4 + ky] = ico[(k0 + ky) * CDIM + j];
    }
    __syncthreads();
    const float4* wsa4 = (const float4*)(wkv_sa + t * CDIM);
    const float4* wda4 = (const float4*)(wkv_da + t * CDIM);
    float as0=0,as1=0,as2=0,as3=0, ad0=0,ad1=0,ad2=0,ad3=0;
    #pragma unroll 4
    for (int j4 = 0; j4 < 32; ++j4) {
      float4 wsv = wsa4[j4];
      float4 wdv = wda4[j4];
      float4 x0 = *(const float4*)&x4[(j4 * 4 + 0) * 4];
      float4 x1 = *(const float4*)&x4[(j4 * 4 + 1) * 4];
      float4 x2 = *(const float4*)&x4[(j4 * 4 + 2) * 4];
      float4 x3 = *(const float4*)&x4[(j4 * 4 + 3) * 4];
      as0 = fmaf(wsv.x, x0.x, as0); as1 = fmaf(wsv.x, x0.y, as1);
      as2 = fmaf(wsv.x, x0.z, as2); as3 = fmaf(wsv.x, x0.w, as3);
      ad0 = fmaf(wdv.x, x0.x, ad0); ad1 = fmaf(wdv.x, x0.y, ad1);
      ad2 = fmaf(wdv.x, x0.z, ad2); ad3 = fmaf(wdv.x, x0.w, ad3);
      as0 = fmaf(wsv.y, x1.x, as0); as1 = fmaf(wsv.y, x1.y, as1);
      as2 = fmaf(wsv.y, x1.z, as2); as3 = fmaf(wsv.y, x1.w, as3);
      ad0 = fmaf(wdv.y, x1.x, ad0); ad1 = fmaf(wdv.y, x1.y, ad1);
      ad2 = fmaf(wdv.y, x1.z, ad2); ad3 = fmaf(wdv.y, x1.w, ad3);
      as0 = fmaf(wsv.z, x2.x, as0); as1 = fmaf(wsv.z, x2.y, as1);
      as2 = fmaf(wsv.z, x2.z, as2); as3 = fmaf(wsv.z, x2.w, as3);
      ad0 = fmaf(wdv.z, x2.x, ad0); ad1 = fmaf(wdv.z, x2.y, ad1);
      ad2 = fmaf(wdv.z, x2.z, ad2); ad3 = fmaf(wdv.z, x2.w, ad3);
      as0 = fmaf(wsv.w, x3.x, as0); as1 = fmaf(wsv.w, x3.y, as1);
      as2 = fmaf(wsv.w, x3.z, as2); as3 = fmaf(wsv.w, x3.w, as3);
      ad0 = fmaf(wdv.w, x3.x, ad0); ad1 = fmaf(wdv.w, x3.y, ad1);
      ad2 = fmaf(wdv.w, x3.z, ad2); ad3 = fmaf(wdv.w, x3.w, ad3);
    }
    if (t < 128) {   // k features -> transposed [c][k], float4 along k
      *(float4*)(ws + OFF_KSAT + t * NKV + k0) = make_float4(as0, as1, as2, as3);
      *(float4*)(ws + OFF_KDAT + t * NKV + k0) = make_float4(ad0, ad1, ad2, ad3);
    } else {         // v features -> [k][c] row-major (coalesced scalar stores)
      int c = t - 128;
      ws[OFF_VSA + (k0 + 0) * CDIM + c] = as0;
      ws[OFF_VSA + (k0 + 1) * CDIM + c] = as1;
      ws[OFF_VSA + (k0 + 2) * CDIM + c] = as2;
      ws[OFF_VSA + (k0 + 3) * CDIM + c] = as3;
      ws[OFF_VDA + (k0 + 0) * CDIM + c] = ad0;
      ws[OFF_VDA + (k0 + 1) * CDIM + c] = ad1;
      ws[OFF_VDA + (k0 + 2) * CDIM + c] = ad2;
      ws[OFF_VDA + (k0 + 3) * CDIM + c] = ad3;
    }
  } else if (bx < 448) {
    // q projection, 4 rows; t<128 -> q_sa out c=t, t>=128 -> q_da out c=t-128
    __shared__ float q4[4 * CDIM];          // [j*4 + r]
    int n0 = (bx - 320) * 4;
    for (int i = t; i < 512; i += 256)
      q4[i] = erp[(i >> 2) * NQ + n0 + (i & 3)];
    __syncthreads();
    const float* w = (t < 128) ? wq_sa : wq_da;
    int c = t & 127;
    const float4* w4 = (const float4*)(w + c * CDIM);
    float a0 = 0.f, a1 = 0.f, a2 = 0.f, a3 = 0.f;
    #pragma unroll 8
    for (int j4 = 0; j4 < 32; ++j4) {
      float4 wv = w4[j4];
      float4 q0 = *(const float4*)&q4[(j4 * 4 + 0) * 4];
      float4 q1 = *(const float4*)&q4[(j4 * 4 + 1) * 4];
      float4 q2 = *(const float4*)&q4[(j4 * 4 + 2) * 4];
      float4 q3 = *(const float4*)&q4[(j4 * 4 + 3) * 4];
      a0 = fmaf(wv.x, q0.x, a0); a1 = fmaf(wv.x, q0.y, a1);
      a2 = fmaf(wv.x, q0.z, a2); a3 = fmaf(wv.x, q0.w, a3);
      a0 = fmaf(wv.y, q1.x, a0); a1 = fmaf(wv.y, q1.y, a1);
      a2 = fmaf(wv.y, q1.z, a2); a3 = fmaf(wv.y, q1.w, a3);
      a0 = fmaf(wv.z, q2.x, a0); a1 = fmaf(wv.z, q2.y, a1);
      a2 = fmaf(wv.z, q2.z, a2); a3 = fmaf(wv.z, q2.w, a3);
      a0 = fmaf(wv.w, q3.x, a0); a1 = fmaf(wv.w, q3.y, a1);
      a2 = fmaf(wv.w, q3.z, a2); a3 = fmaf(wv.w, q3.w, a3);
    }
    float* o = ws + ((t < 128) ? OFF_QSA : OFF_QDA);
    o[(n0 + 0) * CDIM + c] = a0;
    o[(n0 + 1) * CDIM + c] = a1;
    o[(n0 + 2) * CDIM + c] = a2;
    o[(n0 + 3) * CDIM + c] = a3;
  } else if (bx == 448) {
    *(float4*)(ws + OFF_SUMS + t * 4) = make_float4(0.f, 0.f, 0.f, 0.f);
    if (t < 3) {   // Wdelta.sum(0)
      float s = 0.f;
      for (int i = 0; i < 128; ++i) s += wdelta[i * 3 + t];
      ws[OFF_WDSUM + t] = s;
    }
  } else {
    int base = OFF_OUT + (bx - 449) * 1024 + t * 4;
    *(float4*)(ws + base) = make_float4(0.f, 0.f, 0.f, 0.f);
  }
}

// ---------------------------------------------------------------- attn
// 1280 blocks, br = b&1 (da odd / sa even, interleaved for CU mix).
// Each block: 4 q-rows (g = (b>>1)/5), 256-k slice (z = (b>>1)%5).
// Thread t owns key k = k0+t, full 128-j logit (no merge). Score loads from
// K^T[c][k] are lane-contiguous scalars (coalesced); q frags via LDS
// broadcast. __expf everywhere (mul+v_exp). AV: thread (c,h) covers the
// 128-k half h for 4 rows; V[k][c] loads lane-contiguous, se broadcast.
__global__ __launch_bounds__(256) void attn_kernel(
    const float* __restrict__ coord, float* __restrict__ ws)
{
  __shared__ __align__(16) float qjf[128][4];  // [j][r] 2KB, float4 per j
  __shared__ __align__(16) float se[4][256];   // exp(logit) 4KB
  __shared__ float red[4][4];
  __shared__ float qcr[4][3];
  __shared__ float wdl[3];
  int b = blockIdx.x, t = threadIdx.x;
  int br = b & 1;
  int bb = b >> 1;
  int g = bb / 5, z = bb - g * 5;
  int n0 = g * 4, k0 = z * 256;

  const float* qsrc = ws + (br ? OFF_QDA : OFF_QSA);
  {
    int j = t & 127, rh = t >> 7;   // rows rh, rh+2
    qjf[j][rh]     = qsrc[(n0 + rh)     * CDIM + j];
    qjf[j][rh + 2] = qsrc[(n0 + rh + 2) * CDIM + j];
  }
  if (br) {
    if (t < 4) {
      int n = n0 + t;
      float x = (float)(n & 31), y = (float)(n >> 5);
      float u  = (x - 16.5f) * 0.19634954084936207f;  // pi/16
      float vv = (y -  8.5f) * 0.19634954084936207f;
      float cv = cosf(vv);
      qcr[t][0] = cv * sinf(u);
      qcr[t][1] = sinf(vv);
      qcr[t][2] = cv * cosf(u);
    }
    if (t >= 64 && t < 67) wdl[t - 64] = ws[OFF_WDSUM + (t - 64)];
  }
  __syncthreads();

  int k = k0 + t;
  float acc0 = 0.f, acc1 = 0.f, acc2 = 0.f, acc3 = 0.f;

  if (br) {
    const float* kt = ws + OFF_KDAT + k;
    #pragma unroll 4
    for (int j = 0; j < 128; ++j) {
      float kv = kt[j * NKV];              // coalesced: lane stride 4B
      float4 q = *(const float4*)qjf[j];   // wave-uniform broadcast
      acc0 += __expf(-fabsf(q.x - kv));
      acc1 += __expf(-fabsf(q.y - kv));
      acc2 += __expf(-fabsf(q.z - kv));
      acc3 += __expf(-fabsf(q.w - kv));
    }
  } else {
    const float* kt = ws + OFF_KSAT + k;
    #pragma unroll 8
    for (int j = 0; j < 128; ++j) {
      float kv = kt[j * NKV];
      float4 q = *(const float4*)qjf[j];
      acc0 = fmaf(q.x, kv, acc0);
      acc1 = fmaf(q.y, kv, acc1);
      acc2 = fmaf(q.z, kv, acc2);
      acc3 = fmaf(q.w, kv, acc3);
    }
  }

  float e0, e1, e2, e3;
  if (br) {
    float c0 = coord[3 * k], c1 = coord[3 * k + 1], c2 = coord[3 * k + 2];
    float w0 = wdl[0], w1 = wdl[1], w2 = wdl[2];
    float p0 = w0 * __expf(-fabsf(qcr[0][0] - c0))
             + w1 * __expf(-fabsf(qcr[0][1] - c1))
             + w2 * __expf(-fabsf(qcr[0][2] - c2));
    float p1 = w0 * __expf(-fabsf(qcr[1][0] - c0))
             + w1 * __expf(-fabsf(qcr[1][1] - c1))
             + w2 * __expf(-fabsf(qcr[1][2] - c2));
    float p2 = w0 * __expf(-fabsf(qcr[2][0] - c0))
             + w1 * __expf(-fabsf(qcr[2][1] - c1))
             + w2 * __expf(-fabsf(qcr[2][2] - c2));
    float p3 = w0 * __expf(-fabsf(qcr[3][0] - c0))
             + w1 * __expf(-fabsf(qcr[3][1] - c1))
             + w2 * __expf(-fabsf(qcr[3][2] - c2));
    const float i128 = 0.0078125f;        // 1/C
    e0 = __expf((acc0 + p0) * i128);
    e1 = __expf((acc1 + p1) * i128);
    e2 = __expf((acc2 + p2) * i128);
    e3 = __expf((acc3 + p3) * i128);
  } else {
    const float scl = 0.088388347648318447f;  // 128^-0.5
    e0 = __expf(acc0 * scl);
    e1 = __expf(acc1 * scl);
    e2 = __expf(acc2 * scl);
    e3 = __expf(acc3 * scl);
  }
  se[0][t] = e0; se[1][t] = e1; se[2][t] = e2; se[3][t] = e3;

  // wave row-sums -> per-wave partials -> atomicAdd
  float s0 = e0, s1 = e1, s2 = e2, s3 = e3;
  #pragma unroll
  for (int o = 32; o > 0; o >>= 1) {
    s0 += __shfl_down(s0, o, 64); s1 += __shfl_down(s1, o, 64);
    s2 += __shfl_down(s2, o, 64); s3 += __shfl_down(s3, o, 64);
  }
  if ((t & 63) == 0) {
    int w = t >> 6;
    red[w][0] = s0; red[w][1] = s1; red[w][2] = s2; red[w][3] = s3;
  }
  __syncthreads();   // covers se[] and red[]
  if (t < 4)
    atomicAdd(ws + OFF_SUMS + br * 512 + n0 + t,
              red[0][t] + red[1][t] + red[2][t] + red[3][t]);

  // AV: thread (c=t&127, h=t>>7) handles k-half [h*128, h*128+128), 4 rows.
  // V[k][c] scalar loads coalesced; se reads wave-uniform (broadcast).
  int c = t & 127, h = t >> 7;
  int kb = h * 128;
  const float* vp = ws + (br ? OFF_VDA : OFF_VSA) + (k0 + kb) * CDIM + c;
  float a0 = 0.f, a1 = 0.f, a2 = 0.f, a3 = 0.f;
  #pragma unroll 2
  for (int ko = 0; ko < 128; ko += 4) {
    float4 p0 = *(const float4*)&se[0][kb + ko];
    float4 p1 = *(const float4*)&se[1][kb + ko];
    float4 p2 = *(const float4*)&se[2][kb + ko];
    float4 p3 = *(const float4*)&se[3][kb + ko];
    float v0 = vp[(ko + 0) * CDIM];
    float v1 = vp[(ko + 1) * CDIM];
    float v2 = vp[(ko + 2) * CDIM];
    float v3 = vp[(ko + 3) * CDIM];
    a0 = fmaf(p0.x, v0, a0); a0 = fmaf(p0.y, v1, a0);
    a0 = fmaf(p0.z, v2, a0); a0 = fmaf(p0.w, v3, a0);
    a1 = fmaf(p1.x, v0, a1); a1 = fmaf(p1.y, v1, a1);
    a1 = fmaf(p1.z, v2, a1); a1 = fmaf(p1.w, v3, a1);
    a2 = fmaf(p2.x, v0, a2); a2 = fmaf(p2.y, v1, a2);
    a2 = fmaf(p2.z, v2, a2); a2 = fmaf(p2.w, v3, a2);
    a3 = fmaf(p3.x, v0, a3); a3 = fmaf(p3.y, v1, a3);
    a3 = fmaf(p3.z, v2, a3); a3 = fmaf(p3.w, v3, a3);
  }
  float* op = ws + OFF_OUT + br * (NQ * CDIM) + c;
  atomicAdd(op + (n0 + 0) * CDIM, a0);
  atomicAdd(op + (n0 + 1) * CDIM, a1);
  atomicAdd(op + (n0 + 2) * CDIM, a2);
  atomicAdd(op + (n0 + 3) * CDIM, a3);
}

// ---------------------------------------------------------------- finalize
// one block (256 thr) per 2 query rows: normalize (divide by sums) with the
// reference's transpose-reshape on sa, project both, gate, fuse, NCHW store.
__global__ __launch_bounds__(256) void finalize_kernel(
    const float* __restrict__ psa, const float* __restrict__ bsa,
    const float* __restrict__ pda, const float* __restrict__ bda,
    const float* __restrict__ gsa, const float* __restrict__ gda,
    float* __restrict__ out, float* __restrict__ ws)
{
  __shared__ float sain[2][CDIM];
  __shared__ float dain[2][CDIM];
  __shared__ float cat[2][2 * CDIM];
  __shared__ float gl[2][2][CDIM];
  int i0 = blockIdx.x * 2, t = threadIdx.x;
  int h = t >> 7, c = t & 127;
  #pragma unroll
  for (int rr = 0; rr < 2; ++rr) {
    int i = i0 + rr;
    if (h == 0) {
      int row = (i & 3) * 128 + c;
      float s = ws[OFF_SUMS + row];
      sain[rr][c] = ws[OFF_OUT + row * CDIM + (i >> 2)] / s;
    } else {
      float s = ws[OFF_SUMS + 512 + i];
      dain[rr][c] = ws[OFF_OUT + NQ * CDIM + i * CDIM + c] / s;
    }
  }
  __syncthreads();
  {
    const float4* w4 = (const float4*)((h ? pda : psa) + c * CDIM);
    const float* in0 = h ? dain[0] : sain[0];
    const float* in1 = h ? dain[1] : sain[1];
    float a0 = 0, a1 = 0, b0 = 0, b1 = 0;
    #pragma unroll 8
    for (int j4 = 0; j4 < 32; ++j4) {
      float4 wv = w4[j4];
      float4 x0 = *(const float4*)&in0[j4 * 4];
      float4 x1 = *(const float4*)&in1[j4 * 4];
      a0 = fmaf(wv.x, x0.x, a0); a1 = fmaf(wv.y, x0.y, a1);
      a0 = fmaf(wv.z, x0.z, a0); a1 = fmaf(wv.w, x0.w, a1);
      b0 = fmaf(wv.x, x1.x, b0); b1 = fmaf(wv.y, x1.y, b1);
      b0 = fmaf(wv.z, x1.z, b0); b1 = fmaf(wv.w, x1.w, b1);
    }
    float bias = h ? bda[c] : bsa[c];
    cat[0][h * CDIM + c] = bias + a0 + a1;
    cat[1][h * CDIM + c] = bias + b0 + b1;
  }
  __syncthreads();
  {
    const float4* g4 = (const float4*)((h ? gda : gsa) + c * 2 * CDIM);
    float a0 = 0, a1 = 0, b0 = 0, b1 = 0;
    #pragma unroll 8
    for (int j4 = 0; j4 < 64; ++j4) {
      float4 gv = g4[j4];
      float4 c0 = *(const float4*)&cat[0][j4 * 4];
      float4 c1 = *(const float4*)&cat[1][j4 * 4];
      a0 = fmaf(gv.x, c0.x, a0); a1 = fmaf(gv.y, c0.y, a1);
      a0 = fmaf(gv.z, c0.z, a0); a1 = fmaf(gv.w, c0.w, a1);
      b0 = fmaf(gv.x, c1.x, b0); b1 = fmaf(gv.y, c1.y, b1);
      b0 = fmaf(gv.z, c1.z, b0); b1 = fmaf(gv.w, c1.w, b1);
    }
    gl[0][h][c] = 1.0f / (1.0f + __expf(-(a0 + a1)));
    gl[1][h][c] = 1.0f / (1.0f + __expf(-(b0 + b1)));
  }
  __syncthreads();
  {
    int i = i0 + h;
    out[c * NQ + i] = gl[h][0][c] * cat[h][c] + gl[h][1][c] * cat[h][CDIM + c];
  }
}

// ---------------------------------------------------------------- launch
extern "C" void kernel_launch(void* const* d_in, const int* in_sizes, int n_in,
                              void* d_out, int out_size, void* d_ws, size_t ws_size,
                              hipStream_t stream)
{
  (void)in_sizes; (void)n_in; (void)out_size; (void)ws_size;
  const float* erp       = (const float*)d_in[0];
  const float* ico       = (const float*)d_in[1];
  const float* coord     = (const float*)d_in[2];
  const float* wq_sa     = (const float*)d_in[3];
  const float* wkv_sa    = (const float*)d_in[4];
  const float* proj_sa_w = (const float*)d_in[5];
  const float* proj_sa_b = (const float*)d_in[6];
  const float* wq_da     = (const float*)d_in[7];
  const float* wkv_da    = (const float*)d_in[8];
  const float* wdelta    = (const float*)d_in[9];
  const float* proj_da_w = (const float*)d_in[10];
  const float* proj_da_b = (const float*)d_in[11];
  const float* gate_sa   = (const float*)d_in[12];
  const float* gate_da   = (const float*)d_in[13];
  float* out = (float*)d_out;
  float* ws  = (float*)d_ws;

  hipLaunchKernelGGL(prep_kernel, dim3(577), dim3(256), 0, stream,
                     erp, ico, wq_sa, wq_da, wkv_sa, wkv_da, wdelta, ws);
  hipLaunchKernelGGL(attn_kernel, dim3(1280), dim3(256), 0, stream,
                     coord, ws);
  hipLaunchKernelGGL(finalize_kernel, dim3(256), dim3(256), 0, stream,
                     proj_sa_w, proj_sa_b, proj_da_w, proj_da_b,
                     gate_sa, gate_da, out, ws);
}